// Round 13
// baseline (992.645 us; speedup 1.0000x reference)
//
#include <hip/hip_runtime.h>
#include <hip/hip_bf16.h>

// GraphConv: out = verts@W0^T + b0 + scatter_sum_undirected(verts@W1^T + b1)
// V=100000, E=1000000, D=64. fp32 in/out; edges int64 (or int32) detected.
//
// R12 -> R13: global fp32 atomics write through to memory-side (R12: WRITE
// 562MB = 2M x 256B exactly) and per-edge cnt/col atomics have the same
// per-op floor (R10/R11: 80-92MB). So ALL per-edge accumulation moves to
// LDS: 400 fine buckets of 250 vertices; one workgroup per bucket keeps its
// slice (64KB fp32 sums + deg) in LDS, gathers neighbor rows, ds_add_f32
// in a bank-conflict-free permuted layout, then one coalesced writeback.
// fill/gather/col deleted. matvec = R10's verified MFMA kernel.

#define NV 100000
#define NE 1000000
#define DIM 64
#define NTILE (NV / 16)      // 6250 MFMA row-tiles
#define NB 400               // fine buckets
#define VB 250               // vertices per bucket (400*250 = 100000)
#define CAPB_F 8192          // entries per bucket (expected ~5000 +- 70)
#define OCAP 1000000         // overflow list capacity
#define ABLK_F 256
#define CHUNK_F ((NE + ABLK_F - 1) / ABLK_F)   // 3907 edges per bin block

typedef __attribute__((ext_vector_type(8))) short short8;   // 8 bf16
typedef __attribute__((ext_vector_type(4))) float f32x4;

// ---------------------------------------------------------------------------
// Edge-layout detection. int64 words: [a_lo,a_hi,b_lo,b_hi,...], hi==0 always.
// int32 words: odd words random in [0,V). 64 zero odd words => int64.
// ---------------------------------------------------------------------------
__global__ void detect_kernel(const int* __restrict__ edges, int* __restrict__ flag) {
    int v = edges[2 * threadIdx.x + 1];
    unsigned long long any = __ballot(v != 0);
    if (threadIdx.x == 0) *flag = (any == 0ull) ? 1 : 0;  // 1 = int64 layout
}

__device__ __forceinline__ unsigned f2bf1(float f) {  // RNE fp32 -> bf16 bits
    unsigned u = __float_as_uint(f);
    return (u + 0x7fffu + ((u >> 16) & 1u)) >> 16;
}

__device__ __forceinline__ short8 pack_bf8(float4 a, float4 b) {
    short8 r;
    r[0] = (short)f2bf1(a.x); r[1] = (short)f2bf1(a.y);
    r[2] = (short)f2bf1(a.z); r[3] = (short)f2bf1(a.w);
    r[4] = (short)f2bf1(b.x); r[5] = (short)f2bf1(b.y);
    r[6] = (short)f2bf1(b.z); r[7] = (short)f2bf1(b.w);
    return r;
}

// verts (fp32) -> vbf (bf16-packed rows, 2 features per uint, 128 B/row)
__global__ void prep_kernel(const float* __restrict__ verts, uint2* __restrict__ vbf) {
    long i = (long)blockIdx.x * blockDim.x + threadIdx.x;
    if (i < (long)NV * (DIM / 4)) {
        float4 v = ((const float4*)verts)[i];
        uint2 w;
        w.x = f2bf1(v.x) | (f2bf1(v.y) << 16);
        w.y = f2bf1(v.z) | (f2bf1(v.w) << 16);
        vbf[i] = w;
    }
}

// ---------------------------------------------------------------------------
// Fine binning: 256 blocks, two passes. LDS histogram over 400 buckets ->
// one global atomicAdd per (block,bucket) -> sequential packed writes into
// block-exclusive ranges (write-combines). Entry = (t_local<<17) | n.
// Overflow (bucket > CAPB_F) goes to a global (t,n) list.
// ---------------------------------------------------------------------------
__global__ __launch_bounds__(256)
void binf_kernel(const int* __restrict__ edges, unsigned* __restrict__ bins,
                 int* __restrict__ bcur, int* __restrict__ over,
                 int* __restrict__ ocur, const int* __restrict__ flag) {
    __shared__ int lcnt[NB], lbase[NB];
    const bool is64 = (*flag != 0);
    const int tid = threadIdx.x;
    const long lo = (long)blockIdx.x * CHUNK_F;
    const long hi = (lo + CHUNK_F < NE) ? lo + CHUNK_F : NE;

    for (int i = tid; i < NB; i += 256) lcnt[i] = 0;
    __syncthreads();

    for (long e = lo + tid; e < hi; e += 256) {
        int a, b;
        if (is64) { int4 q = ((const int4*)edges)[e]; a = q.x; b = q.z; }
        else      { int2 q = ((const int2*)edges)[e]; a = q.x; b = q.y; }
        atomicAdd(&lcnt[a / VB], 1);
        atomicAdd(&lcnt[b / VB], 1);
    }
    __syncthreads();
    for (int i = tid; i < NB; i += 256) lbase[i] = atomicAdd(&bcur[i], lcnt[i]);
    __syncthreads();
    for (int i = tid; i < NB; i += 256) lcnt[i] = 0;   // reuse as cursor
    __syncthreads();

    for (long e = lo + tid; e < hi; e += 256) {
        int a, b;
        if (is64) { int4 q = ((const int4*)edges)[e]; a = q.x; b = q.z; }
        else      { int2 q = ((const int2*)edges)[e]; a = q.x; b = q.y; }
#pragma unroll
        for (int s = 0; s < 2; ++s) {
            const int t = s ? b : a, n = s ? a : b;
            const int p = t / VB;
            const int idx = lbase[p] + atomicAdd(&lcnt[p], 1);
            if (idx < CAPB_F)
                bins[(long)p * CAPB_F + idx] =
                    ((unsigned)(t - p * VB) << 17) | (unsigned)n;
            else {
                int oi = atomicAdd(ocur, 1);
                if (oi < OCAP) { over[2 * oi] = t; over[2 * oi + 1] = n; }
            }
        }
    }
}

// ---------------------------------------------------------------------------
// LDS-sliced scatter: one workgroup (512 thr = 8 waves) per bucket. Slice
// sums live in LDS in PERMUTED layout: element d=4s+j of vertex t is at
// lsum[t*64 + s + 16*j] -> the 4 ds_adds per lane are lane-stride-1 (2-way
// bank alias = free). Entry broadcast via __shfl always under full exec;
// only the load/accumulate is predicated (R6 discipline).
// ---------------------------------------------------------------------------
__global__ __launch_bounds__(512)
void slds_kernel(const unsigned* __restrict__ bins, const int* __restrict__ bcur,
                 const uint2* __restrict__ vbf2,
                 float* __restrict__ sums, int* __restrict__ cnt) {
    __shared__ float lsum[VB * DIM];   // 64000 B
    __shared__ int   ldeg[VB];         // 1000 B
    const int tid = threadIdx.x;
    const int bkt = blockIdx.x;

    for (int i = tid; i < VB * DIM; i += 512) lsum[i] = 0.f;
    for (int i = tid; i < VB; i += 512) ldeg[i] = 0;
    __syncthreads();

    int nent = bcur[bkt]; if (nent > CAPB_F) nent = CAPB_F;
    const unsigned* mybin = bins + (long)bkt * CAPB_F;
    const int lane = tid & 63;
    const int sub = lane & 15;
    const int grp = lane >> 4;
    const int wavein = tid >> 6;               // 0..7

    const int nchunk = (nent + 63) >> 6;
    for (int ch = wavein; ch < nchunk; ch += 8) {
        const int base = ch << 6;
        const int lim = nent - base > 64 ? 64 : nent - base;   // wave-uniform
        const unsigned myent = mybin[base + (lane < lim ? lane : 0)];
        const int iters = (lim + 3) >> 2;                       // wave-uniform
        for (int i = 0; i < iters; ++i) {
            const int idx = i * 4 + grp;                        // <= 63
            const unsigned e = __shfl(myent, idx, 64);          // full exec
            if (idx < lim) {
                const int t = (int)(e >> 17);
                const int n = (int)(e & 0x1FFFFu);
                const uint2 w = vbf2[(long)n * 16 + sub];       // 128B row
                atomicAdd(&lsum[t * 64 + sub +  0], __uint_as_float(w.x << 16));
                atomicAdd(&lsum[t * 64 + sub + 16], __uint_as_float(w.x & 0xffff0000u));
                atomicAdd(&lsum[t * 64 + sub + 32], __uint_as_float(w.y << 16));
                atomicAdd(&lsum[t * 64 + sub + 48], __uint_as_float(w.y & 0xffff0000u));
                if (sub == 0) atomicAdd(&ldeg[t], 1);
            }
        }
    }
    __syncthreads();

    // Writeback (un-permute): global elem d=4s+j reads lsum[t*64 + s + 16j].
    const long vbase = (long)bkt * VB;
    for (int i = tid; i < VB * DIM; i += 512) {
        const int t = i >> 6, d = i & 63, s = d >> 2, j = d & 3;
        sums[(vbase + t) * DIM + d] = lsum[t * 64 + s + 16 * j];
    }
    for (int i = tid; i < VB; i += 512) cnt[vbase + i] = ldeg[i];
}

// Rare path: overflow entries -> global fp32 atomics (normally zero entries).
__global__ void cleanup_kernel(const float* __restrict__ verts,
                               const int* __restrict__ over,
                               const int* __restrict__ ocur,
                               float* __restrict__ sums, int* __restrict__ cnt) {
    const int lane = threadIdx.x & 63;
    const int wave = (int)((blockIdx.x * blockDim.x + threadIdx.x) >> 6);
    const int nwaves = (int)((gridDim.x * blockDim.x) >> 6);
    int n = *ocur; if (n > OCAP) n = OCAP;
    for (int i = wave; i < n; i += nwaves) {
        const int t = over[2 * i], nb = over[2 * i + 1];
        atomicAdd(&sums[(long)t * DIM + lane], verts[(long)nb * DIM + lane]);
        if (lane == 0) atomicAdd(&cnt[t], 1);
    }
}

// ---------------------------------------------------------------------------
// MFMA matvec (R10, verified): out = [X|S]@[W0;W1]^T + b0 + deg*b1 via
// mfma_f32_16x16x32_bf16, one wave per 16-vertex tile, B-frags hoisted.
// ---------------------------------------------------------------------------
__global__ __launch_bounds__(256)
void matvec_mfma_kernel(const uint2* __restrict__ vbf,
                        const float* __restrict__ sums,
                        const float* __restrict__ w0,
                        const float* __restrict__ b0,
                        const float* __restrict__ w1,
                        const float* __restrict__ b1,
                        const int* __restrict__ cnt,
                        float* __restrict__ out) {
    const int lane = threadIdx.x & 63;
    const int quad = lane >> 4;
    const int n = lane & 15;
    const int wave = (int)((blockIdx.x * blockDim.x + threadIdx.x) >> 6);
    const int nwaves = (int)((gridDim.x * blockDim.x) >> 6);

    short8 B[4][4];
#pragma unroll
    for (int c = 0; c < 4; ++c) {
        const float* wsrc = (c < 2) ? w0 : w1;
        const int kb = (c & 1) * 32 + quad * 8;
#pragma unroll
        for (int t = 0; t < 4; ++t) {
            const int d = t * 16 + n;
            const float4 p = *(const float4*)(wsrc + d * DIM + kb);
            const float4 q = *(const float4*)(wsrc + d * DIM + kb + 4);
            B[c][t] = pack_bf8(p, q);
        }
    }
    float bias0[4], bias1[4];
#pragma unroll
    for (int t = 0; t < 4; ++t) { bias0[t] = b0[t * 16 + n]; bias1[t] = b1[t * 16 + n]; }

    const short8* vb8 = (const short8*)vbf;

    for (int tile = wave; tile < NTILE; tile += nwaves) {
        const int base = tile * 16;
        const long v = base + n;
        f32x4 acc[4] = {{0.f,0.f,0.f,0.f},{0.f,0.f,0.f,0.f},
                        {0.f,0.f,0.f,0.f},{0.f,0.f,0.f,0.f}};

#pragma unroll
        for (int c = 0; c < 2; ++c) {
            const short8 A = vb8[v * 8 + c * 4 + quad];
#pragma unroll
            for (int t = 0; t < 4; ++t)
                acc[t] = __builtin_amdgcn_mfma_f32_16x16x32_bf16(A, B[c][t], acc[t], 0, 0, 0);
        }
#pragma unroll
        for (int c = 2; c < 4; ++c) {
            const int kb = (c - 2) * 32 + quad * 8;
            const float4 p = *(const float4*)(sums + v * DIM + kb);
            const float4 q = *(const float4*)(sums + v * DIM + kb + 4);
            const short8 A = pack_bf8(p, q);
#pragma unroll
            for (int t = 0; t < 4; ++t)
                acc[t] = __builtin_amdgcn_mfma_f32_16x16x32_bf16(A, B[c][t], acc[t], 0, 0, 0);
        }
#pragma unroll
        for (int r = 0; r < 4; ++r) {
            const int row = base + quad * 4 + r;
            const float dg = (float)cnt[row];
#pragma unroll
            for (int t = 0; t < 4; ++t)
                out[(long)row * DIM + t * 16 + n] = acc[t][r] + fmaf(dg, bias1[t], bias0[t]);
        }
    }
}

// ==========================================================================

extern "C" void kernel_launch(void* const* d_in, const int* in_sizes, int n_in,
                              void* d_out, int out_size, void* d_ws, size_t ws_size,
                              hipStream_t stream) {
    const float* verts = (const float*)d_in[0];
    const int*   edges = (const int*)d_in[1];
    const float* w0_w  = (const float*)d_in[2];
    const float* w0_b  = (const float*)d_in[3];
    const float* w1_w  = (const float*)d_in[4];
    const float* w1_b  = (const float*)d_in[5];
    float* out = (float*)d_out;

    // Workspace (~60MB): sums 25.6M | cnt 0.4M | vbf 12.8M | bins_f 13.1M |
    //                    bcur_f 1.6K | ocur | flag | over 8M
    char* p = (char*)d_ws;
    float* sums  = (float*)p;  p += (size_t)NV * DIM * 4;
    int* cnt     = (int*)p;    p += (size_t)NV * 4;
    uint2* vbf   = (uint2*)p;  p += (size_t)NV * DIM * 2;
    unsigned* bins = (unsigned*)p; p += (size_t)NB * CAPB_F * 4;
    int* bcur    = (int*)p;    p += NB * 4;
    int* ocur    = (int*)p;    p += 8;
    int* flag    = (int*)p;    p += 8;
    int* over    = (int*)p;

    // Zero bcur + ocur (+flag, rewritten by detect). sums/cnt fully written
    // by slds_kernel -> no big memset needed.
    hipMemsetAsync(bcur, 0, NB * 4 + 16, stream);
    detect_kernel<<<1, 64, 0, stream>>>(edges, flag);
    prep_kernel<<<(NV * (DIM / 4) + 255) / 256, 256, 0, stream>>>(verts, vbf);
    binf_kernel<<<ABLK_F, 256, 0, stream>>>(edges, bins, bcur, over, ocur, flag);
    slds_kernel<<<NB, 512, 0, stream>>>(bins, bcur, vbf, sums, cnt);
    cleanup_kernel<<<64, 256, 0, stream>>>(verts, over, ocur, sums, cnt);
    matvec_mfma_kernel<<<1563, 256, 0, stream>>>(vbf, sums, w0_w, w0_b,
                                                 w1_w, w1_b, cnt, out);
}